// Round 6
// baseline (681.685 us; speedup 1.0000x reference)
//
#include <hip/hip_runtime.h>
#include <hip/hip_bf16.h>
#include <math.h>

#define N_NODES 100000
#define N_EDGES 1600000
#define D 128
#define NB 391          // scan blocks = ceil(N/256)

// ---- workspace layout (bytes) ----
#define OFF_SSRC 0                    // int[E]      CSR src ids      (6,400,000)
#define OFF_OFFS 6400000              // int[N+1]    CSR offsets
#define OFF_PACK 6800016              // W_pack bf16 hi/lo fragments (393,216)
#define OFF_GC   7193232              // aux[NB] block sums for scan
#define OFF_BB   7195296              // bbase[NB]
#define OFF_M    7204112              // 51.2 MB region: deg/cnt during preproc, then plane-pair B
#define OFF_XHI  58404112             // ushort[N*D]  h hi plane A (25.6 MB)
#define OFF_XLO  84004112             // ushort[N*D]  h lo plane A (25.6 MB)

typedef __attribute__((ext_vector_type(8))) short short8;
typedef __attribute__((ext_vector_type(4))) float floatx4;

__device__ __forceinline__ unsigned short f2bf(float f) {
    unsigned int u = __float_as_uint(f);
    u += 0x7fffu + ((u >> 16) & 1u);   // RNE
    return (unsigned short)(u >> 16);
}
__device__ __forceinline__ float bf2f(unsigned short h) {
    return __uint_as_float(((unsigned int)h) << 16);
}

// ---------------- fp32 x -> bf16 hi/lo planes, + degree histogram folded in ----------------
// Histogram = memset->atomicAdd pattern (proven in part_kernel since round 0).
__global__ __launch_bounds__(256) void cvt_hist_kernel(const float* __restrict__ x,
                                                       unsigned int* __restrict__ Xhi,
                                                       unsigned int* __restrict__ Xlo,
                                                       const int* __restrict__ dst,
                                                       int* __restrict__ deg) {
    int bid = blockIdx.x, t = threadIdx.x;
    if (t < 64) atomicAdd(&deg[dst[bid * 64 + t]], 1);   // 25000*64 == N_EDGES exactly
    int i = bid * 256 + t;                               // N*64 uints, 2 channels each
    float2 v = ((const float2*)x)[i];
    unsigned short h0 = f2bf(v.x), h1 = f2bf(v.y);
    unsigned short l0 = f2bf(v.x - bf2f(h0)), l1 = f2bf(v.y - bf2f(h1));
    Xhi[i] = (unsigned int)h0 | ((unsigned int)h1 << 16);
    Xlo[i] = (unsigned int)l0 | ((unsigned int)l1 << 16);
}

// ---------------- scan level 1: per-256-node exclusive scan + block totals ----------------
__global__ __launch_bounds__(256) void scan1_kernel(const int* __restrict__ deg,
                                                    int* __restrict__ offs,
                                                    int* __restrict__ aux) {
    __shared__ int sh[256];
    int b = blockIdx.x, t = threadIdx.x;
    int node = b * 256 + t;
    int v = (node < N_NODES) ? deg[node] : 0;
    sh[t] = v;
    __syncthreads();
    for (int off = 1; off < 256; off <<= 1) {
        int y = (t >= off) ? sh[t - off] : 0;
        __syncthreads();
        sh[t] += y;
        __syncthreads();
    }
    if (node < N_NODES) offs[node] = sh[t] - v;          // local exclusive prefix
    if (t == 255) aux[b] = sh[255];                      // block total
}

// ---------------- scan level 2: exclusive scan of block totals ----------------
__global__ void bscan_kernel(const int* __restrict__ aux, int* __restrict__ bbase,
                             int* __restrict__ offs) {
    __shared__ int sh[512];
    int t = threadIdx.x;
    int v = (t < NB) ? aux[t] : 0;
    sh[t] = v;
    __syncthreads();
    for (int off = 1; off < 512; off <<= 1) {
        int y = (t >= off) ? sh[t - off] : 0;
        __syncthreads();
        sh[t] += y;
        __syncthreads();
    }
    if (t < NB) bbase[t] = sh[t] - v;
    if (t == 0) offs[N_NODES] = N_EDGES;
}

// ---------------- scan level 3: add block bases ----------------
__global__ __launch_bounds__(256) void scan2_kernel(int* __restrict__ offs,
                                                    const int* __restrict__ bbase) {
    int b = blockIdx.x, t = threadIdx.x;
    int node = b * 256 + t;
    if (node < N_NODES) offs[node] += bbase[b];
}

// ---------------- scatter edges into CSR ----------------
// p = offs[d] (plain read across kernel boundary: proven) + atomicAdd on a freshly
// MEMSET counter (proven memset->atomic pattern). Clamp = OOB containment.
__global__ __launch_bounds__(256) void scatter_kernel(const int* __restrict__ src,
                                                      const int* __restrict__ dst,
                                                      const int* __restrict__ offs,
                                                      int* __restrict__ cnt,
                                                      int* __restrict__ s_src) {
    int t = threadIdx.x;
    int e0 = blockIdx.x * 4096;
#pragma unroll
    for (int i = 0; i < 16; ++i) {
        int e = e0 + i * 256 + t;
        if (e < N_EDGES) {
            int d = dst[e];
            int p = offs[d] + atomicAdd(&cnt[d], 1);
            s_src[min(p, N_EDGES - 1)] = src[e];
        }
    }
}

// ---------------- weight pack: fragment-ordered bf16 hi/lo ----------------
__global__ void pack_kernel(const float* __restrict__ Wl0, const float* __restrict__ Wr0,
                            const float* __restrict__ Wl1, const float* __restrict__ Wr1,
                            const float* __restrict__ Wl2, const float* __restrict__ Wr2,
                            unsigned short* __restrict__ pack) {
    int tid = blockIdx.x * blockDim.x + threadIdx.x;   // 3*32768 threads
    int l = tid >> 15;
    int r = tid & 32767;
    int k = r >> 7;
    int n = r & 127;
    const float* Wl = (l == 0) ? Wl0 : (l == 1) ? Wl1 : Wl2;
    const float* Wr = (l == 0) ? Wr0 : (l == 1) ? Wr1 : Wr2;
    float v = (k < 128) ? Wl[k * 128 + n] : Wr[(k - 128) * 128 + n];
    unsigned short hi = f2bf(v);
    unsigned short lo = f2bf(v - bf2f(hi));
    int ct = n >> 4, ks = k >> 5, lane = ((k >> 3) & 3) * 16 + (n & 15), j = k & 7;
    int idx = ((ct * 8 + ks) * 64 + lane) * 8 + j;
    pack[l * 65536 + idx] = hi;
    pack[l * 65536 + 32768 + idx] = lo;
}

// ---------------- fused layer: mean-gather (LDS) + MFMA linear + LN(+ELU|+L2norm) ----------------
// IDENTICAL to the round-4 passing kernel (expm1f restored). 256 threads (4 waves),
// 64 nodes/block, wave-private LDS, no __syncthreads, 32 KB LDS chunk-XOR swizzle.
__global__ __launch_bounds__(256, 5) void fused_kernel(const uint4* __restrict__ X4,   // = Xh as rows
                                                       const unsigned short* __restrict__ Xh,
                                                       const unsigned short* __restrict__ Xl,
                                                       unsigned short* __restrict__ XhO,
                                                       unsigned short* __restrict__ XlO,
                                                       const int* __restrict__ s_src,
                                                       const int* __restrict__ offs,
                                                       const unsigned short* __restrict__ packh,
                                                       const unsigned short* __restrict__ packl,
                                                       const float* __restrict__ bl,
                                                       const float* __restrict__ g,
                                                       const float* __restrict__ b,
                                                       float* __restrict__ outf, int last) {
    __shared__ float lmean[64 * 128];              // 32,768 B exactly
    int t = threadIdx.x;
    int wid = t >> 6, lane = t & 63;
    int sub = lane >> 4, li = lane & 15;
    int nodebase = blockIdx.x * 64;

    // ---- phase 1: mean aggregation for this wave's 16 nodes ----
    int off_l = offs[min(nodebase + wid * 16 + min(lane, 16), N_NODES)];

#define ACC_U4(u)                                                                  \
    do {                                                                           \
        const unsigned int w_[4] = {(u).x, (u).y, (u).z, (u).w};                   \
        _Pragma("unroll") for (int j_ = 0; j_ < 4; ++j_) {                         \
            acc[2 * j_]     += bf2f((unsigned short)w_[j_]);                       \
            acc[2 * j_ + 1] += bf2f((unsigned short)(w_[j_] >> 16));               \
        }                                                                          \
    } while (0)

    for (int i = 0; i < 16; ++i) {
        int lrow = wid * 16 + i;
        int beg = __shfl(off_l, i);
        int end = __shfl(off_l, i + 1);
        int deg = end - beg;                       // 0 for clamped tail nodes
        float acc[8];
#pragma unroll
        for (int j = 0; j < 8; ++j) acc[j] = 0.f;

        for (int cbase = 0; cbase < deg; cbase += 64) {
            int cnt = min(deg - cbase, 64);
            int myidx = s_src[min(beg + cbase + lane, N_EDGES - 1)];
            int j = 0;
            for (; j + 16 <= cnt; j += 16) {       // 16 edges, 4 loads in flight
                int i0 = __shfl(myidx, j + sub);
                int i1 = __shfl(myidx, j + 4 + sub);
                int i2 = __shfl(myidx, j + 8 + sub);
                int i3 = __shfl(myidx, j + 12 + sub);
                uint4 u0 = X4[i0 * 16 + li];
                uint4 u1 = X4[i1 * 16 + li];
                uint4 u2 = X4[i2 * 16 + li];
                uint4 u3 = X4[i3 * 16 + li];
                ACC_U4(u0); ACC_U4(u1); ACC_U4(u2); ACC_U4(u3);
            }
            if (j + 8 <= cnt) {
                int i0 = __shfl(myidx, j + sub);
                int i1 = __shfl(myidx, j + 4 + sub);
                uint4 u0 = X4[i0 * 16 + li];
                uint4 u1 = X4[i1 * 16 + li];
                ACC_U4(u0); ACC_U4(u1);
                j += 8;
            }
            if (j + 4 <= cnt) {
                int i0 = __shfl(myidx, j + sub);
                uint4 u0 = X4[i0 * 16 + li];
                ACC_U4(u0);
                j += 4;
            }
            int rem = cnt - j;
            if (rem > 0) {                         // wave-uniform; tail 1..3 edges
                int i0 = __shfl(myidx, j + min(sub, rem - 1));
                uint4 u0 = X4[i0 * 16 + li];
                if (sub < rem) ACC_U4(u0);
            }
        }
        // combine the 4 subgroup partials (lanes li, li+16, li+32, li+48)
#pragma unroll
        for (int j = 0; j < 8; ++j) {
            acc[j] += __shfl_xor(acc[j], 16);
            acc[j] += __shfl_xor(acc[j], 32);
        }
        float inv = 1.0f / fmaxf((float)deg, 1.0f);
        if (sub < 2) {
            int chunk = li * 2 + sub;              // 16 B chunk index within row
            floatx4 v = {acc[sub * 4] * inv, acc[sub * 4 + 1] * inv,
                         acc[sub * 4 + 2] * inv, acc[sub * 4 + 3] * inv};
            *(floatx4*)&lmean[lrow * 128 + ((chunk ^ (lrow & 7)) << 2)] = v;
        }
    }
#undef ACC_U4
    // no __syncthreads: each wave reads only the LDS rows it just wrote

    // ---- phase 2: MFMA linear + LN epilogue (A ks0..3 from LDS, 16 rows/wave) ----
    int colb = lane & 15;
    int quad = lane >> 4;
    int kq = quad * 8;
    int tilebase = nodebase + wid * 16;

    int rowA = min(tilebase + colb, N_NODES - 1);
    int lrowA = wid * 16 + colb;
    int rsalt = lrowA & 7;

    floatx4 acc[8];
#pragma unroll
    for (int ct = 0; ct < 8; ++ct) acc[ct] = (floatx4){0.f, 0.f, 0.f, 0.f};

    // ---- ks 0..3: mean @ Wl (fp32 mean from LDS -> split hi/lo in-register) ----
#pragma unroll
    for (int ks = 0; ks < 4; ++ks) {
        int chunk0 = ks * 8 + quad * 2;
        short8 ah, al;
        {
            floatx4 v0 = *(const floatx4*)&lmean[lrowA * 128 + ((chunk0 ^ rsalt) << 2)];
            floatx4 v1 = *(const floatx4*)&lmean[lrowA * 128 + (((chunk0 + 1) ^ rsalt) << 2)];
            float v[8] = {v0[0], v0[1], v0[2], v0[3], v1[0], v1[1], v1[2], v1[3]};
#pragma unroll
            for (int j = 0; j < 8; ++j) {
                unsigned short hi = f2bf(v[j]);
                ah[j] = (short)hi;
                al[j] = (short)f2bf(v[j] - bf2f(hi));
            }
        }
#pragma unroll
        for (int ct = 0; ct < 8; ++ct) {
            int fo = ((ct * 8 + ks) << 9) + (lane << 3);
            short8 bh = *(const short8*)(packh + fo);
            short8 bo = *(const short8*)(packl + fo);
            acc[ct] = __builtin_amdgcn_mfma_f32_16x16x32_bf16(ah, bh, acc[ct], 0, 0, 0);
            acc[ct] = __builtin_amdgcn_mfma_f32_16x16x32_bf16(al, bh, acc[ct], 0, 0, 0);
            acc[ct] = __builtin_amdgcn_mfma_f32_16x16x32_bf16(ah, bo, acc[ct], 0, 0, 0);
        }
    }
    // ---- ks 4..7: h @ Wr (hi/lo planes loaded directly as fragments) ----
#pragma unroll
    for (int ks = 4; ks < 8; ++ks) {
        int kof = (ks - 4) * 32 + kq;
        long o = (long)rowA * D + kof;
        short8 ah = *(const short8*)(Xh + o);
        short8 al = *(const short8*)(Xl + o);
#pragma unroll
        for (int ct = 0; ct < 8; ++ct) {
            int fo = ((ct * 8 + ks) << 9) + (lane << 3);
            short8 bh = *(const short8*)(packh + fo);
            short8 bo = *(const short8*)(packl + fo);
            acc[ct] = __builtin_amdgcn_mfma_f32_16x16x32_bf16(ah, bh, acc[ct], 0, 0, 0);
            acc[ct] = __builtin_amdgcn_mfma_f32_16x16x32_bf16(al, bh, acc[ct], 0, 0, 0);
            acc[ct] = __builtin_amdgcn_mfma_f32_16x16x32_bf16(ah, bo, acc[ct], 0, 0, 0);
        }
    }

    float bb[8], gg[8], b2[8];
#pragma unroll
    for (int ct = 0; ct < 8; ++ct) {
        bb[ct] = bl[ct * 16 + colb];
        gg[ct] = g[ct * 16 + colb];
        b2[ct] = b[ct * 16 + colb];
    }

#pragma unroll
    for (int ct = 0; ct < 8; ++ct)
#pragma unroll
        for (int e = 0; e < 4; ++e) acc[ct][e] += bb[ct];
    float mu[4], rstd[4];
#pragma unroll
    for (int e = 0; e < 4; ++e) {
        float s = 0.f;
#pragma unroll
        for (int ct = 0; ct < 8; ++ct) s += acc[ct][e];
        s += __shfl_xor(s, 1); s += __shfl_xor(s, 2);
        s += __shfl_xor(s, 4); s += __shfl_xor(s, 8);
        mu[e] = s * (1.0f / 128.0f);
    }
#pragma unroll
    for (int e = 0; e < 4; ++e) {
        float q = 0.f;
#pragma unroll
        for (int ct = 0; ct < 8; ++ct) {
            float d = acc[ct][e] - mu[e];
            q += d * d;
        }
        q += __shfl_xor(q, 1); q += __shfl_xor(q, 2);
        q += __shfl_xor(q, 4); q += __shfl_xor(q, 8);
        rstd[e] = rsqrtf(q * (1.0f / 128.0f) + 1e-5f);
    }
#pragma unroll
    for (int ct = 0; ct < 8; ++ct)
#pragma unroll
        for (int e = 0; e < 4; ++e) {
            float y = (acc[ct][e] - mu[e]) * rstd[e] * gg[ct] + b2[ct];
            if (!last) y = (y > 0.f) ? y : expm1f(y);
            acc[ct][e] = y;
        }
    if (last) {
#pragma unroll
        for (int e = 0; e < 4; ++e) {
            float ss = 0.f;
#pragma unroll
            for (int ct = 0; ct < 8; ++ct) {
                float y = acc[ct][e];
                ss += y * y;
            }
            ss += __shfl_xor(ss, 1); ss += __shfl_xor(ss, 2);
            ss += __shfl_xor(ss, 4); ss += __shfl_xor(ss, 8);
            float inv = 1.0f / fmaxf(sqrtf(ss), 1e-12f);
#pragma unroll
            for (int ct = 0; ct < 8; ++ct) acc[ct][e] *= inv;
        }
#pragma unroll
        for (int e = 0; e < 4; ++e) {
            int row = tilebase + quad * 4 + e;
            if (row < N_NODES) {
#pragma unroll
                for (int ct = 0; ct < 8; ++ct)
                    outf[(long)row * D + ct * 16 + colb] = acc[ct][e];
            }
        }
    } else {
#pragma unroll
        for (int e = 0; e < 4; ++e) {
            int row = tilebase + quad * 4 + e;
            if (row < N_NODES) {
#pragma unroll
                for (int ct = 0; ct < 8; ++ct) {
                    float y = acc[ct][e];
                    unsigned short hh = f2bf(y);
                    unsigned short ll = f2bf(y - bf2f(hh));
                    long o = (long)row * D + ct * 16 + colb;
                    XhO[o] = hh;
                    XlO[o] = ll;
                }
            }
        }
    }
}

extern "C" void kernel_launch(void* const* d_in, const int* in_sizes, int n_in,
                              void* d_out, int out_size, void* d_ws, size_t ws_size,
                              hipStream_t stream) {
    const float* x = (const float*)d_in[0];
    const int* edges = (const int*)d_in[1];
    const int* src = edges;
    const int* dst = edges + N_EDGES;
    const float* Wl[3] = {(const float*)d_in[2], (const float*)d_in[7],  (const float*)d_in[12]};
    const float* bl[3] = {(const float*)d_in[3], (const float*)d_in[8],  (const float*)d_in[13]};
    const float* Wr[3] = {(const float*)d_in[4], (const float*)d_in[9],  (const float*)d_in[14]};
    const float* g[3]  = {(const float*)d_in[5], (const float*)d_in[10], (const float*)d_in[15]};
    const float* b[3]  = {(const float*)d_in[6], (const float*)d_in[11], (const float*)d_in[16]};

    char* ws = (char*)d_ws;
    int* s_src = (int*)(ws + OFF_SSRC);
    int* offs  = (int*)(ws + OFF_OFFS);
    unsigned short* wpack = (unsigned short*)(ws + OFF_PACK);
    int* aux   = (int*)(ws + OFF_GC);
    int* bbase = (int*)(ws + OFF_BB);
    int* deg   = (int*)(ws + OFF_M);                               // preproc only
    int* cnt   = (int*)(ws + OFF_M + 400000);                      // preproc only
    unsigned short* XhB = (unsigned short*)(ws + OFF_M);           // plane pair B (after preproc)
    unsigned short* XlB = (unsigned short*)(ws + OFF_M + 25600000);
    unsigned short* XhA = (unsigned short*)(ws + OFF_XHI);         // plane pair A
    unsigned short* XlA = (unsigned short*)(ws + OFF_XLO);
    float* out = (float*)d_out;

    // ---- CSR build: global-atomic counting sort (memset->atomic pattern only) ----
    hipMemsetAsync(deg, 0, 2 * N_NODES * sizeof(int), stream);     // zeroes deg AND cnt
    cvt_hist_kernel<<<(N_NODES * 64) / 256, 256, 0, stream>>>(x, (unsigned int*)XhA,
                                                              (unsigned int*)XlA, dst, deg);
    scan1_kernel<<<NB, 256, 0, stream>>>(deg, offs, aux);
    bscan_kernel<<<1, 512, 0, stream>>>(aux, bbase, offs);
    scan2_kernel<<<NB, 256, 0, stream>>>(offs, bbase);
    pack_kernel<<<(3 * 32768) / 256, 256, 0, stream>>>(Wl[0], Wr[0], Wl[1], Wr[1], Wl[2], Wr[2], wpack);
    scatter_kernel<<<(N_EDGES + 4095) / 4096, 256, 0, stream>>>(src, dst, offs, cnt, s_src);

    const int FB = (N_NODES + 63) / 64;  // 1563
    unsigned short* ph[3] = {wpack, wpack + 65536, wpack + 131072};

    // ---- layer 0: read planes A -> write planes B ----
    fused_kernel<<<FB, 256, 0, stream>>>((const uint4*)XhA, XhA, XlA, XhB, XlB,
                                         s_src, offs, ph[0], ph[0] + 32768,
                                         bl[0], g[0], b[0], nullptr, 0);
    // ---- layer 1: read planes B -> write planes A ----
    fused_kernel<<<FB, 256, 0, stream>>>((const uint4*)XhB, XhB, XlB, XhA, XlA,
                                         s_src, offs, ph[1], ph[1] + 32768,
                                         bl[1], g[1], b[1], nullptr, 0);
    // ---- layer 2: read planes A -> write out (fp32) ----
    fused_kernel<<<FB, 256, 0, stream>>>((const uint4*)XhA, XhA, XlA, nullptr, nullptr,
                                         s_src, offs, ph[2], ph[2] + 32768,
                                         bl[2], g[2], b[2], out, 1);
}

// Round 7
// 593.230 us; speedup vs baseline: 1.1491x; 1.1491x over previous
//
#include <hip/hip_runtime.h>
#include <hip/hip_bf16.h>
#include <math.h>

#define N_NODES 100000
#define N_EDGES 1600000
#define D 128
#define NB 391          // buckets = ceil(N/256), bucket = dst >> 8
#define BSTRIDE 6000    // staging cap/bucket (avg 4092, sigma 64 -> 14 sigma headroom)

// ---- workspace layout (bytes) ----
#define OFF_SSRC 0                    // int[E]      sorted src ids   (6,400,000)
#define OFF_OFFS 6400000              // int[N+1]    CSR offsets
#define OFF_PACK 6800016              // W_pack bf16 hi/lo fragments (393,216)
#define OFF_GC   7193232              // gcur[NB]
#define OFF_BB   7195296              // bbase[NB]
#define OFF_M    7204112              // 51.2 MB region: sort staging (18.8 MB), then plane-pair B
#define OFF_XHI  58404112             // ushort[N*D]  h hi plane A (25.6 MB)
#define OFF_XLO  84004112             // ushort[N*D]  h lo plane A (25.6 MB)

typedef __attribute__((ext_vector_type(8))) short short8;
typedef __attribute__((ext_vector_type(4))) float floatx4;

__device__ __forceinline__ unsigned short f2bf(float f) {
    unsigned int u = __float_as_uint(f);
    u += 0x7fffu + ((u >> 16) & 1u);   // RNE
    return (unsigned short)(u >> 16);
}
__device__ __forceinline__ float bf2f(unsigned short h) {
    return __uint_as_float(((unsigned int)h) << 16);
}

// ---------------- pass 1: partition edges into 391 coarse buckets ----------------
__global__ __launch_bounds__(256) void part_kernel(const int* __restrict__ src,
                                                   const int* __restrict__ dst,
                                                   int* __restrict__ gcur,
                                                   uint2* __restrict__ staging) {
    __shared__ int hist[NB];
    __shared__ int base[NB];
    int t = threadIdx.x;
    int e0 = blockIdx.x * 4096;
    for (int i = t; i < NB; i += 256) hist[i] = 0;
    __syncthreads();
    int d[16];
#pragma unroll
    for (int i = 0; i < 16; ++i) {
        int e = e0 + i * 256 + t;
        d[i] = (e < N_EDGES) ? dst[e] : -1;
        if (d[i] >= 0) atomicAdd(&hist[d[i] >> 8], 1);
    }
    __syncthreads();
    for (int i = t; i < NB; i += 256) {
        int h = hist[i];
        base[i] = h ? atomicAdd(&gcur[i], h) : 0;
    }
    __syncthreads();
    for (int i = t; i < NB; i += 256) hist[i] = 0;   // reuse as local cursor
    __syncthreads();
#pragma unroll
    for (int i = 0; i < 16; ++i) {
        if (d[i] >= 0) {
            int e = e0 + i * 256 + t;
            int b = d[i] >> 8;
            int slot = atomicAdd(&hist[b], 1);
            staging[b * BSTRIDE + base[b] + slot] =
                make_uint2((unsigned)src[e], (unsigned)(d[i] & 255));
        }
    }
}

// ---------------- exclusive scan of bucket totals ----------------
__global__ void bscan_kernel(const int* __restrict__ gcur, int* __restrict__ bbase,
                             int* __restrict__ offs) {
    __shared__ int sh[512];
    int t = threadIdx.x;
    int v = (t < NB) ? gcur[t] : 0;
    sh[t] = v;
    __syncthreads();
    for (int off = 1; off < 512; off <<= 1) {
        int y = (t >= off) ? sh[t - off] : 0;
        __syncthreads();
        sh[t] += y;
        __syncthreads();
    }
    if (t < NB) bbase[t] = sh[t] - v;
    if (t == 0) offs[N_NODES] = N_EDGES;
}

// ---------------- pass 2: sort each bucket in LDS, emit CSR ----------------
__global__ __launch_bounds__(256) void bsort_kernel(const uint2* __restrict__ staging,
                                                    const int* __restrict__ gcur,
                                                    const int* __restrict__ bbase,
                                                    int* __restrict__ offs,
                                                    int* __restrict__ s_src) {
    __shared__ int cnt[256];
    __shared__ int scn[256];
    __shared__ int ssrc[BSTRIDE];
    int b = blockIdx.x;
    int t = threadIdx.x;
    int n = gcur[b];
    int base_out = bbase[b];
    cnt[t] = 0;
    __syncthreads();
    for (int e = t; e < n; e += 256) {
        uint2 v = staging[b * BSTRIDE + e];
        atomicAdd(&cnt[v.y], 1);
    }
    __syncthreads();
    int v = cnt[t];
    scn[t] = v;
    __syncthreads();
    for (int off = 1; off < 256; off <<= 1) {
        int y = (t >= off) ? scn[t - off] : 0;
        __syncthreads();
        scn[t] += y;
        __syncthreads();
    }
    int ex = scn[t] - v;                 // exclusive prefix
    int node = b * 256 + t;
    if (node < N_NODES) offs[node] = base_out + ex;
    cnt[t] = ex;                         // reuse as cursor
    __syncthreads();
    for (int e = t; e < n; e += 256) {
        uint2 w = staging[b * BSTRIDE + e];
        int slot = atomicAdd(&cnt[w.y], 1);
        ssrc[slot] = (int)w.x;
    }
    __syncthreads();
    for (int e = t; e < n; e += 256) s_src[base_out + e] = ssrc[e];
}

// ---------------- weight pack: fragment-ordered bf16 hi/lo ----------------
__global__ void pack_kernel(const float* __restrict__ Wl0, const float* __restrict__ Wr0,
                            const float* __restrict__ Wl1, const float* __restrict__ Wr1,
                            const float* __restrict__ Wl2, const float* __restrict__ Wr2,
                            unsigned short* __restrict__ pack) {
    int tid = blockIdx.x * blockDim.x + threadIdx.x;   // 3*32768 threads
    int l = tid >> 15;
    int r = tid & 32767;
    int k = r >> 7;
    int n = r & 127;
    const float* Wl = (l == 0) ? Wl0 : (l == 1) ? Wl1 : Wl2;
    const float* Wr = (l == 0) ? Wr0 : (l == 1) ? Wr1 : Wr2;
    float v = (k < 128) ? Wl[k * 128 + n] : Wr[(k - 128) * 128 + n];
    unsigned short hi = f2bf(v);
    unsigned short lo = f2bf(v - bf2f(hi));
    int ct = n >> 4, ks = k >> 5, lane = ((k >> 3) & 3) * 16 + (n & 15), j = k & 7;
    int idx = ((ct * 8 + ks) * 64 + lane) * 8 + j;
    pack[l * 65536 + idx] = hi;
    pack[l * 65536 + 32768 + idx] = lo;
}

// ---------------- fp32 x -> bf16 hi/lo planes ----------------
__global__ __launch_bounds__(256) void cvt_kernel(const float* __restrict__ x,
                                                  unsigned int* __restrict__ Xhi,
                                                  unsigned int* __restrict__ Xlo) {
    int i = blockIdx.x * 256 + threadIdx.x;      // N*64 uints, 2 channels each
    float2 v = ((const float2*)x)[i];
    unsigned short h0 = f2bf(v.x), h1 = f2bf(v.y);
    unsigned short l0 = f2bf(v.x - bf2f(h0)), l1 = f2bf(v.y - bf2f(h1));
    Xhi[i] = (unsigned int)h0 | ((unsigned int)h1 << 16);
    Xlo[i] = (unsigned int)l0 | ((unsigned int)l1 << 16);
}

// ---------------- fused layer: mean-gather (LDS) + MFMA linear + LN(+ELU|+L2norm) ----------------
// v5: 128-thread blocks (2 waves), 32 nodes/block -> grid 3125 (2x finer tail
// granularity vs round 4's 1563; theoretical residency unchanged at 20 waves/CU:
// 10 blocks x 2 waves, LDS 16 KB). Wave-private LDS (each wave gathers its 16
// nodes, then consumes the same 16 rows) -> NO __syncthreads. Chunk-XOR swizzle.
__global__ __launch_bounds__(128, 5) void fused_kernel(const uint4* __restrict__ X4,   // = Xh as rows
                                                       const unsigned short* __restrict__ Xh,
                                                       const unsigned short* __restrict__ Xl,
                                                       unsigned short* __restrict__ XhO,
                                                       unsigned short* __restrict__ XlO,
                                                       const int* __restrict__ s_src,
                                                       const int* __restrict__ offs,
                                                       const unsigned short* __restrict__ packh,
                                                       const unsigned short* __restrict__ packl,
                                                       const float* __restrict__ bl,
                                                       const float* __restrict__ g,
                                                       const float* __restrict__ b,
                                                       float* __restrict__ outf, int last) {
    __shared__ float lmean[32 * 128];              // 16,384 B
    int t = threadIdx.x;
    int wid = t >> 6, lane = t & 63;
    int sub = lane >> 4, li = lane & 15;
    int nodebase = blockIdx.x * 32;

    // ---- phase 1: mean aggregation for this wave's 16 nodes ----
    int off_l = offs[min(nodebase + wid * 16 + min(lane, 16), N_NODES)];

#define ACC_U4(u)                                                                  \
    do {                                                                           \
        const unsigned int w_[4] = {(u).x, (u).y, (u).z, (u).w};                   \
        _Pragma("unroll") for (int j_ = 0; j_ < 4; ++j_) {                         \
            acc[2 * j_]     += bf2f((unsigned short)w_[j_]);                       \
            acc[2 * j_ + 1] += bf2f((unsigned short)(w_[j_] >> 16));               \
        }                                                                          \
    } while (0)

    for (int i = 0; i < 16; ++i) {
        int lrow = wid * 16 + i;
        int beg = __shfl(off_l, i);
        int end = __shfl(off_l, i + 1);
        int deg = end - beg;                       // 0 for clamped tail nodes
        float acc[8];
#pragma unroll
        for (int j = 0; j < 8; ++j) acc[j] = 0.f;

        for (int cbase = 0; cbase < deg; cbase += 64) {
            int cnt = min(deg - cbase, 64);
            int myidx = s_src[min(beg + cbase + lane, N_EDGES - 1)];
            int j = 0;
            for (; j + 16 <= cnt; j += 16) {       // 16 edges, 4 loads in flight
                int i0 = __shfl(myidx, j + sub);
                int i1 = __shfl(myidx, j + 4 + sub);
                int i2 = __shfl(myidx, j + 8 + sub);
                int i3 = __shfl(myidx, j + 12 + sub);
                uint4 u0 = X4[i0 * 16 + li];
                uint4 u1 = X4[i1 * 16 + li];
                uint4 u2 = X4[i2 * 16 + li];
                uint4 u3 = X4[i3 * 16 + li];
                ACC_U4(u0); ACC_U4(u1); ACC_U4(u2); ACC_U4(u3);
            }
            if (j + 8 <= cnt) {
                int i0 = __shfl(myidx, j + sub);
                int i1 = __shfl(myidx, j + 4 + sub);
                uint4 u0 = X4[i0 * 16 + li];
                uint4 u1 = X4[i1 * 16 + li];
                ACC_U4(u0); ACC_U4(u1);
                j += 8;
            }
            if (j + 4 <= cnt) {
                int i0 = __shfl(myidx, j + sub);
                uint4 u0 = X4[i0 * 16 + li];
                ACC_U4(u0);
                j += 4;
            }
            int rem = cnt - j;
            if (rem > 0) {                         // wave-uniform; tail 1..3 edges
                int i0 = __shfl(myidx, j + min(sub, rem - 1));
                uint4 u0 = X4[i0 * 16 + li];
                if (sub < rem) ACC_U4(u0);
            }
        }
        // combine the 4 subgroup partials (lanes li, li+16, li+32, li+48)
#pragma unroll
        for (int j = 0; j < 8; ++j) {
            acc[j] += __shfl_xor(acc[j], 16);
            acc[j] += __shfl_xor(acc[j], 32);
        }
        float inv = 1.0f / fmaxf((float)deg, 1.0f);
        if (sub < 2) {
            int chunk = li * 2 + sub;              // 16 B chunk index within row
            floatx4 v = {acc[sub * 4] * inv, acc[sub * 4 + 1] * inv,
                         acc[sub * 4 + 2] * inv, acc[sub * 4 + 3] * inv};
            *(floatx4*)&lmean[lrow * 128 + ((chunk ^ (lrow & 7)) << 2)] = v;
        }
    }
#undef ACC_U4
    // no __syncthreads: each wave reads only the LDS rows it just wrote

    // ---- phase 2: MFMA linear + LN epilogue (A ks0..3 from LDS, 16 rows/wave) ----
    int colb = lane & 15;
    int quad = lane >> 4;
    int kq = quad * 8;
    int tilebase = nodebase + wid * 16;

    int rowA = min(tilebase + colb, N_NODES - 1);
    int lrowA = wid * 16 + colb;
    int rsalt = lrowA & 7;

    floatx4 acc[8];
#pragma unroll
    for (int ct = 0; ct < 8; ++ct) acc[ct] = (floatx4){0.f, 0.f, 0.f, 0.f};

    // ---- ks 0..3: mean @ Wl (fp32 mean from LDS -> split hi/lo in-register) ----
#pragma unroll
    for (int ks = 0; ks < 4; ++ks) {
        int chunk0 = ks * 8 + quad * 2;
        short8 ah, al;
        {
            floatx4 v0 = *(const floatx4*)&lmean[lrowA * 128 + ((chunk0 ^ rsalt) << 2)];
            floatx4 v1 = *(const floatx4*)&lmean[lrowA * 128 + (((chunk0 + 1) ^ rsalt) << 2)];
            float v[8] = {v0[0], v0[1], v0[2], v0[3], v1[0], v1[1], v1[2], v1[3]};
#pragma unroll
            for (int j = 0; j < 8; ++j) {
                unsigned short hi = f2bf(v[j]);
                ah[j] = (short)hi;
                al[j] = (short)f2bf(v[j] - bf2f(hi));
            }
        }
#pragma unroll
        for (int ct = 0; ct < 8; ++ct) {
            int fo = ((ct * 8 + ks) << 9) + (lane << 3);
            short8 bh = *(const short8*)(packh + fo);
            short8 bo = *(const short8*)(packl + fo);
            acc[ct] = __builtin_amdgcn_mfma_f32_16x16x32_bf16(ah, bh, acc[ct], 0, 0, 0);
            acc[ct] = __builtin_amdgcn_mfma_f32_16x16x32_bf16(al, bh, acc[ct], 0, 0, 0);
            acc[ct] = __builtin_amdgcn_mfma_f32_16x16x32_bf16(ah, bo, acc[ct], 0, 0, 0);
        }
    }
    // ---- ks 4..7: h @ Wr (hi/lo planes loaded directly as fragments) ----
#pragma unroll
    for (int ks = 4; ks < 8; ++ks) {
        int kof = (ks - 4) * 32 + kq;
        long o = (long)rowA * D + kof;
        short8 ah = *(const short8*)(Xh + o);
        short8 al = *(const short8*)(Xl + o);
#pragma unroll
        for (int ct = 0; ct < 8; ++ct) {
            int fo = ((ct * 8 + ks) << 9) + (lane << 3);
            short8 bh = *(const short8*)(packh + fo);
            short8 bo = *(const short8*)(packl + fo);
            acc[ct] = __builtin_amdgcn_mfma_f32_16x16x32_bf16(ah, bh, acc[ct], 0, 0, 0);
            acc[ct] = __builtin_amdgcn_mfma_f32_16x16x32_bf16(al, bh, acc[ct], 0, 0, 0);
            acc[ct] = __builtin_amdgcn_mfma_f32_16x16x32_bf16(ah, bo, acc[ct], 0, 0, 0);
        }
    }

    float bb[8], gg[8], b2[8];
#pragma unroll
    for (int ct = 0; ct < 8; ++ct) {
        bb[ct] = bl[ct * 16 + colb];
        gg[ct] = g[ct * 16 + colb];
        b2[ct] = b[ct * 16 + colb];
    }

#pragma unroll
    for (int ct = 0; ct < 8; ++ct)
#pragma unroll
        for (int e = 0; e < 4; ++e) acc[ct][e] += bb[ct];
    float mu[4], rstd[4];
#pragma unroll
    for (int e = 0; e < 4; ++e) {
        float s = 0.f;
#pragma unroll
        for (int ct = 0; ct < 8; ++ct) s += acc[ct][e];
        s += __shfl_xor(s, 1); s += __shfl_xor(s, 2);
        s += __shfl_xor(s, 4); s += __shfl_xor(s, 8);
        mu[e] = s * (1.0f / 128.0f);
    }
#pragma unroll
    for (int e = 0; e < 4; ++e) {
        float q = 0.f;
#pragma unroll
        for (int ct = 0; ct < 8; ++ct) {
            float d = acc[ct][e] - mu[e];
            q += d * d;
        }
        q += __shfl_xor(q, 1); q += __shfl_xor(q, 2);
        q += __shfl_xor(q, 4); q += __shfl_xor(q, 8);
        rstd[e] = rsqrtf(q * (1.0f / 128.0f) + 1e-5f);
    }
#pragma unroll
    for (int ct = 0; ct < 8; ++ct)
#pragma unroll
        for (int e = 0; e < 4; ++e) {
            float y = (acc[ct][e] - mu[e]) * rstd[e] * gg[ct] + b2[ct];
            if (!last) y = (y > 0.f) ? y : expm1f(y);
            acc[ct][e] = y;
        }
    if (last) {
#pragma unroll
        for (int e = 0; e < 4; ++e) {
            float ss = 0.f;
#pragma unroll
            for (int ct = 0; ct < 8; ++ct) {
                float y = acc[ct][e];
                ss += y * y;
            }
            ss += __shfl_xor(ss, 1); ss += __shfl_xor(ss, 2);
            ss += __shfl_xor(ss, 4); ss += __shfl_xor(ss, 8);
            float inv = 1.0f / fmaxf(sqrtf(ss), 1e-12f);
#pragma unroll
            for (int ct = 0; ct < 8; ++ct) acc[ct][e] *= inv;
        }
#pragma unroll
        for (int e = 0; e < 4; ++e) {
            int row = tilebase + quad * 4 + e;
            if (row < N_NODES) {
#pragma unroll
                for (int ct = 0; ct < 8; ++ct)
                    outf[(long)row * D + ct * 16 + colb] = acc[ct][e];
            }
        }
    } else {
#pragma unroll
        for (int e = 0; e < 4; ++e) {
            int row = tilebase + quad * 4 + e;
            if (row < N_NODES) {
#pragma unroll
                for (int ct = 0; ct < 8; ++ct) {
                    float y = acc[ct][e];
                    unsigned short hh = f2bf(y);
                    unsigned short ll = f2bf(y - bf2f(hh));
                    long o = (long)row * D + ct * 16 + colb;
                    XhO[o] = hh;
                    XlO[o] = ll;
                }
            }
        }
    }
}

extern "C" void kernel_launch(void* const* d_in, const int* in_sizes, int n_in,
                              void* d_out, int out_size, void* d_ws, size_t ws_size,
                              hipStream_t stream) {
    const float* x = (const float*)d_in[0];
    const int* edges = (const int*)d_in[1];
    const int* src = edges;
    const int* dst = edges + N_EDGES;
    const float* Wl[3] = {(const float*)d_in[2], (const float*)d_in[7],  (const float*)d_in[12]};
    const float* bl[3] = {(const float*)d_in[3], (const float*)d_in[8],  (const float*)d_in[13]};
    const float* Wr[3] = {(const float*)d_in[4], (const float*)d_in[9],  (const float*)d_in[14]};
    const float* g[3]  = {(const float*)d_in[5], (const float*)d_in[10], (const float*)d_in[15]};
    const float* b[3]  = {(const float*)d_in[6], (const float*)d_in[11], (const float*)d_in[16]};

    char* ws = (char*)d_ws;
    int* s_src = (int*)(ws + OFF_SSRC);
    int* offs  = (int*)(ws + OFF_OFFS);
    unsigned short* wpack = (unsigned short*)(ws + OFF_PACK);
    int* gcur  = (int*)(ws + OFF_GC);
    int* bbase = (int*)(ws + OFF_BB);
    uint2* staging = (uint2*)(ws + OFF_M);              // dead after bsort
    unsigned short* XhB = (unsigned short*)(ws + OFF_M);           // plane pair B (aliases staging)
    unsigned short* XlB = (unsigned short*)(ws + OFF_M + 25600000);
    unsigned short* XhA = (unsigned short*)(ws + OFF_XHI);         // plane pair A
    unsigned short* XlA = (unsigned short*)(ws + OFF_XLO);
    float* out = (float*)d_out;

    // ---- locality-preserving bucket sort of edges by dst (round-4 proven path) ----
    hipMemsetAsync(gcur, 0, NB * sizeof(int), stream);
    part_kernel<<<(N_EDGES + 4095) / 4096, 256, 0, stream>>>(src, dst, gcur, staging);
    bscan_kernel<<<1, 512, 0, stream>>>(gcur, bbase, offs);
    bsort_kernel<<<NB, 256, 0, stream>>>(staging, gcur, bbase, offs, s_src);
    // weights -> bf16 hi/lo fragments; x -> bf16 hi/lo planes (pair A)
    pack_kernel<<<(3 * 32768) / 256, 256, 0, stream>>>(Wl[0], Wr[0], Wl[1], Wr[1], Wl[2], Wr[2], wpack);
    cvt_kernel<<<(N_NODES * 64) / 256, 256, 0, stream>>>(x, (unsigned int*)XhA, (unsigned int*)XlA);

    const int FB = (N_NODES + 31) / 32;  // 3125
    unsigned short* ph[3] = {wpack, wpack + 65536, wpack + 131072};

    // ---- layer 0: read planes A -> write planes B ----
    fused_kernel<<<FB, 128, 0, stream>>>((const uint4*)XhA, XhA, XlA, XhB, XlB,
                                         s_src, offs, ph[0], ph[0] + 32768,
                                         bl[0], g[0], b[0], nullptr, 0);
    // ---- layer 1: read planes B -> write planes A ----
    fused_kernel<<<FB, 128, 0, stream>>>((const uint4*)XhB, XhB, XlB, XhA, XlA,
                                         s_src, offs, ph[1], ph[1] + 32768,
                                         bl[1], g[1], b[1], nullptr, 0);
    // ---- layer 2: read planes A -> write out (fp32) ----
    fused_kernel<<<FB, 128, 0, stream>>>((const uint4*)XhA, XhA, XlA, nullptr, nullptr,
                                         s_src, offs, ph[2], ph[2] + 32768,
                                         bl[2], g[2], b[2], out, 1);
}

// Round 8
// 583.765 us; speedup vs baseline: 1.1677x; 1.0162x over previous
//
#include <hip/hip_runtime.h>
#include <hip/hip_bf16.h>
#include <math.h>

#define N_NODES 100000
#define N_EDGES 1600000
#define D 128
#define NB 391          // buckets = ceil(N/256), bucket = dst >> 8
#define BSTRIDE 6000    // staging cap/bucket (avg 4092, sigma 64 -> 14 sigma headroom)

// ---- workspace layout (bytes) ----
#define OFF_SSRC 0                    // int[E]      sorted src ids   (6,400,000)
#define OFF_OFFS 6400000              // int[N+1]    CSR offsets
#define OFF_PACK 6800016              // W_pack bf16 hi/lo fragments (393,216)
#define OFF_GC   7193232              // gcur[NB]
#define OFF_BB   7195296              // bbase[NB]
#define OFF_M    7204112              // 51.2 MB region: sort staging (9.4 MB), then plane-pair B
#define OFF_XHI  58404112             // ushort[N*D]  h hi plane A (25.6 MB)
#define OFF_XLO  84004112             // ushort[N*D]  h lo plane A (25.6 MB)

typedef __attribute__((ext_vector_type(8))) short short8;
typedef __attribute__((ext_vector_type(4))) float floatx4;

__device__ __forceinline__ unsigned short f2bf(float f) {
    unsigned int u = __float_as_uint(f);
    u += 0x7fffu + ((u >> 16) & 1u);   // RNE
    return (unsigned short)(u >> 16);
}
__device__ __forceinline__ float bf2f(unsigned short h) {
    return __uint_as_float(((unsigned int)h) << 16);
}

// ---------------- merged prep: part (edges->buckets) + weight pack + x->planes ----------------
// Role by blockIdx: [0,391) part, [391,775) pack, [775,25775) cvt. Branches are
// block-uniform so intra-role __syncthreads is legal. cvt's 25000 BW-bound blocks
// backfill CUs around part's 391 low-parallelism blocks (overlap, not serialize).
// Staging entry packed to 4 B: (src << 8) | (dst & 255); src < 2^17.
__global__ __launch_bounds__(256) void prep_kernel(const int* __restrict__ src,
                                                   const int* __restrict__ dst,
                                                   int* __restrict__ gcur,
                                                   unsigned int* __restrict__ staging,
                                                   const float* __restrict__ Wl0, const float* __restrict__ Wr0,
                                                   const float* __restrict__ Wl1, const float* __restrict__ Wr1,
                                                   const float* __restrict__ Wl2, const float* __restrict__ Wr2,
                                                   unsigned short* __restrict__ wpack,
                                                   const float* __restrict__ x,
                                                   unsigned int* __restrict__ Xhi,
                                                   unsigned int* __restrict__ Xlo) {
    int bid = blockIdx.x;
    int t = threadIdx.x;
    if (bid < NB) {
        // ---- part: partition 4096 edges into 391 coarse buckets ----
        __shared__ int hist[NB];
        __shared__ int base[NB];
        int e0 = bid * 4096;
        for (int i = t; i < NB; i += 256) hist[i] = 0;
        __syncthreads();
        int d[16];
#pragma unroll
        for (int i = 0; i < 16; ++i) {
            int e = e0 + i * 256 + t;
            d[i] = (e < N_EDGES) ? dst[e] : -1;
            if (d[i] >= 0) atomicAdd(&hist[d[i] >> 8], 1);
        }
        __syncthreads();
        for (int i = t; i < NB; i += 256) {
            int h = hist[i];
            base[i] = h ? atomicAdd(&gcur[i], h) : 0;
        }
        __syncthreads();
        for (int i = t; i < NB; i += 256) hist[i] = 0;   // reuse as local cursor
        __syncthreads();
#pragma unroll
        for (int i = 0; i < 16; ++i) {
            if (d[i] >= 0) {
                int e = e0 + i * 256 + t;
                int b = d[i] >> 8;
                int slot = atomicAdd(&hist[b], 1);
                staging[b * BSTRIDE + base[b] + slot] =
                    ((unsigned int)src[e] << 8) | (unsigned int)(d[i] & 255);
            }
        }
    } else if (bid < NB + 384) {
        // ---- pack: weights -> fragment-ordered bf16 hi/lo ----
        int tid = (bid - NB) * 256 + t;                  // 3*32768 threads
        int l = tid >> 15;
        int r = tid & 32767;
        int k = r >> 7;
        int n = r & 127;
        const float* Wl = (l == 0) ? Wl0 : (l == 1) ? Wl1 : Wl2;
        const float* Wr = (l == 0) ? Wr0 : (l == 1) ? Wr1 : Wr2;
        float v = (k < 128) ? Wl[k * 128 + n] : Wr[(k - 128) * 128 + n];
        unsigned short hi = f2bf(v);
        unsigned short lo = f2bf(v - bf2f(hi));
        int ct = n >> 4, ks = k >> 5, lane = ((k >> 3) & 3) * 16 + (n & 15), j = k & 7;
        int idx = ((ct * 8 + ks) * 64 + lane) * 8 + j;
        wpack[l * 65536 + idx] = hi;
        wpack[l * 65536 + 32768 + idx] = lo;
    } else {
        // ---- cvt: fp32 x -> bf16 hi/lo planes ----
        int i = (bid - NB - 384) * 256 + t;              // N*64 uints, 2 channels each
        float2 v = ((const float2*)x)[i];
        unsigned short h0 = f2bf(v.x), h1 = f2bf(v.y);
        unsigned short l0 = f2bf(v.x - bf2f(h0)), l1 = f2bf(v.y - bf2f(h1));
        Xhi[i] = (unsigned int)h0 | ((unsigned int)h1 << 16);
        Xlo[i] = (unsigned int)l0 | ((unsigned int)l1 << 16);
    }
}

// ---------------- exclusive scan of bucket totals ----------------
__global__ void bscan_kernel(const int* __restrict__ gcur, int* __restrict__ bbase,
                             int* __restrict__ offs) {
    __shared__ int sh[512];
    int t = threadIdx.x;
    int v = (t < NB) ? gcur[t] : 0;
    sh[t] = v;
    __syncthreads();
    for (int off = 1; off < 512; off <<= 1) {
        int y = (t >= off) ? sh[t - off] : 0;
        __syncthreads();
        sh[t] += y;
        __syncthreads();
    }
    if (t < NB) bbase[t] = sh[t] - v;
    if (t == 0) offs[N_NODES] = N_EDGES;
}

// ---------------- pass 2: sort each bucket in LDS, emit CSR (1024 threads) ----------------
// 1024 threads/block -> 2 blocks/CU (wave-capped) -> all 391 blocks resident in ONE
// cohort (vs 256t version's 2-cohort imbalance), and per-block latency quartered.
__global__ __launch_bounds__(1024) void bsort_kernel(const unsigned int* __restrict__ staging,
                                                     const int* __restrict__ gcur,
                                                     const int* __restrict__ bbase,
                                                     int* __restrict__ offs,
                                                     int* __restrict__ s_src) {
    __shared__ int cnt[256];
    __shared__ int scn[256];
    __shared__ int ssrc[BSTRIDE];
    int b = blockIdx.x;
    int t = threadIdx.x;
    int n = gcur[b];
    int base_out = bbase[b];
    if (t < 256) cnt[t] = 0;
    __syncthreads();
    for (int e = t; e < n; e += 1024)
        atomicAdd(&cnt[staging[b * BSTRIDE + e] & 255u], 1);
    __syncthreads();
    int v = 0;
    if (t < 256) { v = cnt[t]; scn[t] = v; }
    __syncthreads();
    for (int off = 1; off < 256; off <<= 1) {
        int y = 0;
        if (t < 256 && t >= off) y = scn[t - off];
        __syncthreads();
        if (t < 256) scn[t] += y;
        __syncthreads();
    }
    if (t < 256) {
        int ex = scn[t] - v;                 // exclusive prefix
        int node = b * 256 + t;
        if (node < N_NODES) offs[node] = base_out + ex;
        cnt[t] = ex;                         // reuse as cursor
    }
    __syncthreads();
    for (int e = t; e < n; e += 1024) {
        unsigned int w = staging[b * BSTRIDE + e];
        int slot = atomicAdd(&cnt[w & 255u], 1);
        ssrc[slot] = (int)(w >> 8);
    }
    __syncthreads();
    for (int e = t; e < n; e += 1024) s_src[base_out + e] = ssrc[e];
}

// ---------------- fused layer: mean-gather (LDS) + MFMA linear + LN(+ELU|+L2norm) ----------------
// UNCHANGED from round 7 (at its structural duty-cycle ceiling): 128-thread blocks
// (2 waves), 32 nodes/block, wave-private LDS, no __syncthreads, chunk-XOR swizzle.
__global__ __launch_bounds__(128, 5) void fused_kernel(const uint4* __restrict__ X4,   // = Xh as rows
                                                       const unsigned short* __restrict__ Xh,
                                                       const unsigned short* __restrict__ Xl,
                                                       unsigned short* __restrict__ XhO,
                                                       unsigned short* __restrict__ XlO,
                                                       const int* __restrict__ s_src,
                                                       const int* __restrict__ offs,
                                                       const unsigned short* __restrict__ packh,
                                                       const unsigned short* __restrict__ packl,
                                                       const float* __restrict__ bl,
                                                       const float* __restrict__ g,
                                                       const float* __restrict__ b,
                                                       float* __restrict__ outf, int last) {
    __shared__ float lmean[32 * 128];              // 16,384 B
    int t = threadIdx.x;
    int wid = t >> 6, lane = t & 63;
    int sub = lane >> 4, li = lane & 15;
    int nodebase = blockIdx.x * 32;

    // ---- phase 1: mean aggregation for this wave's 16 nodes ----
    int off_l = offs[min(nodebase + wid * 16 + min(lane, 16), N_NODES)];

#define ACC_U4(u)                                                                  \
    do {                                                                           \
        const unsigned int w_[4] = {(u).x, (u).y, (u).z, (u).w};                   \
        _Pragma("unroll") for (int j_ = 0; j_ < 4; ++j_) {                         \
            acc[2 * j_]     += bf2f((unsigned short)w_[j_]);                       \
            acc[2 * j_ + 1] += bf2f((unsigned short)(w_[j_] >> 16));               \
        }                                                                          \
    } while (0)

    for (int i = 0; i < 16; ++i) {
        int lrow = wid * 16 + i;
        int beg = __shfl(off_l, i);
        int end = __shfl(off_l, i + 1);
        int deg = end - beg;                       // 0 for clamped tail nodes
        float acc[8];
#pragma unroll
        for (int j = 0; j < 8; ++j) acc[j] = 0.f;

        for (int cbase = 0; cbase < deg; cbase += 64) {
            int cnt = min(deg - cbase, 64);
            int myidx = s_src[min(beg + cbase + lane, N_EDGES - 1)];
            int j = 0;
            for (; j + 16 <= cnt; j += 16) {       // 16 edges, 4 loads in flight
                int i0 = __shfl(myidx, j + sub);
                int i1 = __shfl(myidx, j + 4 + sub);
                int i2 = __shfl(myidx, j + 8 + sub);
                int i3 = __shfl(myidx, j + 12 + sub);
                uint4 u0 = X4[i0 * 16 + li];
                uint4 u1 = X4[i1 * 16 + li];
                uint4 u2 = X4[i2 * 16 + li];
                uint4 u3 = X4[i3 * 16 + li];
                ACC_U4(u0); ACC_U4(u1); ACC_U4(u2); ACC_U4(u3);
            }
            if (j + 8 <= cnt) {
                int i0 = __shfl(myidx, j + sub);
                int i1 = __shfl(myidx, j + 4 + sub);
                uint4 u0 = X4[i0 * 16 + li];
                uint4 u1 = X4[i1 * 16 + li];
                ACC_U4(u0); ACC_U4(u1);
                j += 8;
            }
            if (j + 4 <= cnt) {
                int i0 = __shfl(myidx, j + sub);
                uint4 u0 = X4[i0 * 16 + li];
                ACC_U4(u0);
                j += 4;
            }
            int rem = cnt - j;
            if (rem > 0) {                         // wave-uniform; tail 1..3 edges
                int i0 = __shfl(myidx, j + min(sub, rem - 1));
                uint4 u0 = X4[i0 * 16 + li];
                if (sub < rem) ACC_U4(u0);
            }
        }
        // combine the 4 subgroup partials (lanes li, li+16, li+32, li+48)
#pragma unroll
        for (int j = 0; j < 8; ++j) {
            acc[j] += __shfl_xor(acc[j], 16);
            acc[j] += __shfl_xor(acc[j], 32);
        }
        float inv = 1.0f / fmaxf((float)deg, 1.0f);
        if (sub < 2) {
            int chunk = li * 2 + sub;              // 16 B chunk index within row
            floatx4 v = {acc[sub * 4] * inv, acc[sub * 4 + 1] * inv,
                         acc[sub * 4 + 2] * inv, acc[sub * 4 + 3] * inv};
            *(floatx4*)&lmean[lrow * 128 + ((chunk ^ (lrow & 7)) << 2)] = v;
        }
    }
#undef ACC_U4
    // no __syncthreads: each wave reads only the LDS rows it just wrote

    // ---- phase 2: MFMA linear + LN epilogue (A ks0..3 from LDS, 16 rows/wave) ----
    int colb = lane & 15;
    int quad = lane >> 4;
    int kq = quad * 8;
    int tilebase = nodebase + wid * 16;

    int rowA = min(tilebase + colb, N_NODES - 1);
    int lrowA = wid * 16 + colb;
    int rsalt = lrowA & 7;

    floatx4 acc[8];
#pragma unroll
    for (int ct = 0; ct < 8; ++ct) acc[ct] = (floatx4){0.f, 0.f, 0.f, 0.f};

    // ---- ks 0..3: mean @ Wl (fp32 mean from LDS -> split hi/lo in-register) ----
#pragma unroll
    for (int ks = 0; ks < 4; ++ks) {
        int chunk0 = ks * 8 + quad * 2;
        short8 ah, al;
        {
            floatx4 v0 = *(const floatx4*)&lmean[lrowA * 128 + ((chunk0 ^ rsalt) << 2)];
            floatx4 v1 = *(const floatx4*)&lmean[lrowA * 128 + (((chunk0 + 1) ^ rsalt) << 2)];
            float v[8] = {v0[0], v0[1], v0[2], v0[3], v1[0], v1[1], v1[2], v1[3]};
#pragma unroll
            for (int j = 0; j < 8; ++j) {
                unsigned short hi = f2bf(v[j]);
                ah[j] = (short)hi;
                al[j] = (short)f2bf(v[j] - bf2f(hi));
            }
        }
#pragma unroll
        for (int ct = 0; ct < 8; ++ct) {
            int fo = ((ct * 8 + ks) << 9) + (lane << 3);
            short8 bh = *(const short8*)(packh + fo);
            short8 bo = *(const short8*)(packl + fo);
            acc[ct] = __builtin_amdgcn_mfma_f32_16x16x32_bf16(ah, bh, acc[ct], 0, 0, 0);
            acc[ct] = __builtin_amdgcn_mfma_f32_16x16x32_bf16(al, bh, acc[ct], 0, 0, 0);
            acc[ct] = __builtin_amdgcn_mfma_f32_16x16x32_bf16(ah, bo, acc[ct], 0, 0, 0);
        }
    }
    // ---- ks 4..7: h @ Wr (hi/lo planes loaded directly as fragments) ----
#pragma unroll
    for (int ks = 4; ks < 8; ++ks) {
        int kof = (ks - 4) * 32 + kq;
        long o = (long)rowA * D + kof;
        short8 ah = *(const short8*)(Xh + o);
        short8 al = *(const short8*)(Xl + o);
#pragma unroll
        for (int ct = 0; ct < 8; ++ct) {
            int fo = ((ct * 8 + ks) << 9) + (lane << 3);
            short8 bh = *(const short8*)(packh + fo);
            short8 bo = *(const short8*)(packl + fo);
            acc[ct] = __builtin_amdgcn_mfma_f32_16x16x32_bf16(ah, bh, acc[ct], 0, 0, 0);
            acc[ct] = __builtin_amdgcn_mfma_f32_16x16x32_bf16(al, bh, acc[ct], 0, 0, 0);
            acc[ct] = __builtin_amdgcn_mfma_f32_16x16x32_bf16(ah, bo, acc[ct], 0, 0, 0);
        }
    }

    float bb[8], gg[8], b2[8];
#pragma unroll
    for (int ct = 0; ct < 8; ++ct) {
        bb[ct] = bl[ct * 16 + colb];
        gg[ct] = g[ct * 16 + colb];
        b2[ct] = b[ct * 16 + colb];
    }

#pragma unroll
    for (int ct = 0; ct < 8; ++ct)
#pragma unroll
        for (int e = 0; e < 4; ++e) acc[ct][e] += bb[ct];
    float mu[4], rstd[4];
#pragma unroll
    for (int e = 0; e < 4; ++e) {
        float s = 0.f;
#pragma unroll
        for (int ct = 0; ct < 8; ++ct) s += acc[ct][e];
        s += __shfl_xor(s, 1); s += __shfl_xor(s, 2);
        s += __shfl_xor(s, 4); s += __shfl_xor(s, 8);
        mu[e] = s * (1.0f / 128.0f);
    }
#pragma unroll
    for (int e = 0; e < 4; ++e) {
        float q = 0.f;
#pragma unroll
        for (int ct = 0; ct < 8; ++ct) {
            float d = acc[ct][e] - mu[e];
            q += d * d;
        }
        q += __shfl_xor(q, 1); q += __shfl_xor(q, 2);
        q += __shfl_xor(q, 4); q += __shfl_xor(q, 8);
        rstd[e] = rsqrtf(q * (1.0f / 128.0f) + 1e-5f);
    }
#pragma unroll
    for (int ct = 0; ct < 8; ++ct)
#pragma unroll
        for (int e = 0; e < 4; ++e) {
            float y = (acc[ct][e] - mu[e]) * rstd[e] * gg[ct] + b2[ct];
            if (!last) y = (y > 0.f) ? y : expm1f(y);
            acc[ct][e] = y;
        }
    if (last) {
#pragma unroll
        for (int e = 0; e < 4; ++e) {
            float ss = 0.f;
#pragma unroll
            for (int ct = 0; ct < 8; ++ct) {
                float y = acc[ct][e];
                ss += y * y;
            }
            ss += __shfl_xor(ss, 1); ss += __shfl_xor(ss, 2);
            ss += __shfl_xor(ss, 4); ss += __shfl_xor(ss, 8);
            float inv = 1.0f / fmaxf(sqrtf(ss), 1e-12f);
#pragma unroll
            for (int ct = 0; ct < 8; ++ct) acc[ct][e] *= inv;
        }
#pragma unroll
        for (int e = 0; e < 4; ++e) {
            int row = tilebase + quad * 4 + e;
            if (row < N_NODES) {
#pragma unroll
                for (int ct = 0; ct < 8; ++ct)
                    outf[(long)row * D + ct * 16 + colb] = acc[ct][e];
            }
        }
    } else {
#pragma unroll
        for (int e = 0; e < 4; ++e) {
            int row = tilebase + quad * 4 + e;
            if (row < N_NODES) {
#pragma unroll
                for (int ct = 0; ct < 8; ++ct) {
                    float y = acc[ct][e];
                    unsigned short hh = f2bf(y);
                    unsigned short ll = f2bf(y - bf2f(hh));
                    long o = (long)row * D + ct * 16 + colb;
                    XhO[o] = hh;
                    XlO[o] = ll;
                }
            }
        }
    }
}

extern "C" void kernel_launch(void* const* d_in, const int* in_sizes, int n_in,
                              void* d_out, int out_size, void* d_ws, size_t ws_size,
                              hipStream_t stream) {
    const float* x = (const float*)d_in[0];
    const int* edges = (const int*)d_in[1];
    const int* src = edges;
    const int* dst = edges + N_EDGES;
    const float* Wl[3] = {(const float*)d_in[2], (const float*)d_in[7],  (const float*)d_in[12]};
    const float* bl[3] = {(const float*)d_in[3], (const float*)d_in[8],  (const float*)d_in[13]};
    const float* Wr[3] = {(const float*)d_in[4], (const float*)d_in[9],  (const float*)d_in[14]};
    const float* g[3]  = {(const float*)d_in[5], (const float*)d_in[10], (const float*)d_in[15]};
    const float* b[3]  = {(const float*)d_in[6], (const float*)d_in[11], (const float*)d_in[16]};

    char* ws = (char*)d_ws;
    int* s_src = (int*)(ws + OFF_SSRC);
    int* offs  = (int*)(ws + OFF_OFFS);
    unsigned short* wpack = (unsigned short*)(ws + OFF_PACK);
    int* gcur  = (int*)(ws + OFF_GC);
    int* bbase = (int*)(ws + OFF_BB);
    unsigned int* staging = (unsigned int*)(ws + OFF_M);           // dead after bsort
    unsigned short* XhB = (unsigned short*)(ws + OFF_M);           // plane pair B (aliases staging)
    unsigned short* XlB = (unsigned short*)(ws + OFF_M + 25600000);
    unsigned short* XhA = (unsigned short*)(ws + OFF_XHI);         // plane pair A
    unsigned short* XlA = (unsigned short*)(ws + OFF_XLO);
    float* out = (float*)d_out;

    // ---- preproc: merged part+pack+cvt, then scan, then bucket sort ----
    hipMemsetAsync(gcur, 0, NB * sizeof(int), stream);
    prep_kernel<<<NB + 384 + 25000, 256, 0, stream>>>(src, dst, gcur, staging,
                                                      Wl[0], Wr[0], Wl[1], Wr[1], Wl[2], Wr[2],
                                                      wpack, x, (unsigned int*)XhA,
                                                      (unsigned int*)XlA);
    bscan_kernel<<<1, 512, 0, stream>>>(gcur, bbase, offs);
    bsort_kernel<<<NB, 1024, 0, stream>>>(staging, gcur, bbase, offs, s_src);

    const int FB = (N_NODES + 31) / 32;  // 3125
    unsigned short* ph[3] = {wpack, wpack + 65536, wpack + 131072};

    // ---- layer 0: read planes A -> write planes B ----
    fused_kernel<<<FB, 128, 0, stream>>>((const uint4*)XhA, XhA, XlA, XhB, XlB,
                                         s_src, offs, ph[0], ph[0] + 32768,
                                         bl[0], g[0], b[0], nullptr, 0);
    // ---- layer 1: read planes B -> write planes A ----
    fused_kernel<<<FB, 128, 0, stream>>>((const uint4*)XhB, XhB, XlB, XhA, XlA,
                                         s_src, offs, ph[1], ph[1] + 32768,
                                         bl[1], g[1], b[1], nullptr, 0);
    // ---- layer 2: read planes A -> write out (fp32) ----
    fused_kernel<<<FB, 128, 0, stream>>>((const uint4*)XhA, XhA, XlA, nullptr, nullptr,
                                         s_src, offs, ph[2], ph[2] + 32768,
                                         bl[2], g[2], b[2], out, 1);
}